// Round 10
// baseline (295.818 us; speedup 1.0000x reference)
//
#include <hip/hip_runtime.h>
#include <stdint.h>

// KANLinear fused MFMA GEMM, R14: K-split waves + 2 blocks/CU.
//   R13 raw-count post-mortem: per SIMD only ~620 cyc MFMA + ~2300 VALU of each
//   8000-cyc superstep; >60% = both resident waves stalled (1 block/CU -> 2
//   waves/SIMD). Fix = TLP from 2 independent blocks, enabled by K-SPLIT:
//   8 waves = 2 kh x 4 wn, each wave does all 64 rows x its 64-col quarter over
//   HALF of K. -> B loads dedup'd (64KB/chunk/CU), A reads halve, B dbuf 32
//   VGPR, ~115 VGPR total -> launch_bounds(512,4) = 4 waves/SIMD (2 domains).
//   Epilogue: kh-pair acc reduction via LDS (2 rounds, one-time).
//   64x256 tile, 512 thr, grid 512 (2 blk/CU), LDS 32 KB (A 4-buf only).
//   C = A @ W^T, A (B x 2304) = [silu(x) | bases(x)], W (256 x 2304) bf16 in ws.

#define IN_F 256
#define OUT_F 256
#define KDIM 2304 /* 256 silu + 256*8 basis */
#define BK 64
#define NCHUNK (KDIM / BK) /* 36 */

typedef float f32x4 __attribute__((ext_vector_type(4)));
typedef short bf16x8 __attribute__((ext_vector_type(8)));

__device__ __forceinline__ uint32_t f2bf(float f) {
    union { float f; uint32_t u; } c; c.f = f;
    uint32_t u = c.u;
    return (u + 0x7FFFu + ((u >> 16) & 1u)) >> 16;   // RNE
}

__device__ __forceinline__ uint32_t cvtpk(float lo, float hi) {
    uint32_t r;
    asm("v_cvt_pk_bf16_f32 %0, %1, %2" : "=v"(r) : "v"(lo), "v"(hi));
    return r;
}

__device__ __forceinline__ float silu_f(float v) {
    return v / (1.0f + __expf(-v));
}

// LDS-only block barrier: waits LDS ops but leaves the VMEM queue in flight.
__device__ __forceinline__ void block_sync_lds() {
    __builtin_amdgcn_sched_barrier(0);
    asm volatile("s_waitcnt lgkmcnt(0)" ::: "memory");
    __builtin_amdgcn_sched_barrier(0);
    __builtin_amdgcn_s_barrier();
    __builtin_amdgcn_sched_barrier(0);
}

// cubic B-spline: 16B fragment (8 bf16 coef slots) for one (row, feat) element.
__device__ __forceinline__ uint4 basis16(float xx) {
    float u = __builtin_fmaf(xx, 2.5f, 5.5f);   // (x - grid0)/h
    float jf = floorf(u);
    float t = u - jf;
    int j0 = (int)jf;
    float t2 = t * t, t3 = t2 * t;
    float p3 = t3 * (1.0f / 6.0f);
    float p2 = __builtin_fmaf(t3, -0.5f,
               __builtin_fmaf(t2, 0.5f, __builtin_fmaf(t, 0.5f, 1.0f / 6.0f)));
    float p1 = __builtin_fmaf(t3, 0.5f, __builtin_fmaf(t2, -1.0f, 2.0f / 3.0f));
    float omt = 1.0f - t;
    float p0 = omt * omt * omt * (1.0f / 6.0f);
    const int s0 = j0 - 3;
    int ds = s0 >> 1;                            // arithmetic: floor-div ok
    if ((unsigned)j0 > 10u) ds = 9;              // out of grid -> no dword match
    const bool odd = (s0 & 1) != 0;
    uint32_t v0 = cvtpk(odd ? 0.0f : p0, odd ? p0 : p1);
    uint32_t v1 = cvtpk(odd ? p1 : p2, odd ? p2 : p3);
    uint32_t v2 = odd ? cvtpk(p3, 0.0f) : 0u;
    uint4 r;
    r.x = (ds == 0) ? v0 : (ds == -1) ? v1 : (ds == -2) ? v2 : 0u;
    r.y = (ds == 1) ? v0 : (ds ==  0) ? v1 : (ds == -1) ? v2 : 0u;
    r.z = (ds == 2) ? v0 : (ds ==  1) ? v1 : (ds ==  0) ? v2 : 0u;
    r.w = (ds == 3) ? v0 : (ds ==  2) ? v1 : (ds ==  1) ? v2 : 0u;
    return r;
}

// fragment-native Wc address (bf16 units): W[col][kc*64+kkh*32+q*8+e]
__device__ __forceinline__ size_t wcf_addr(int col, int k) {
    const int kc = k >> 6, kkh = (k >> 5) & 1, q = (k >> 3) & 3, e = k & 7;
    return ((size_t)((kc * 2 + kkh) * 16 + (col >> 4))) * 512 +
           (size_t)(q * 16 + (col & 15)) * 8 + e;
}

// ---------------- kernel 1: fragment-native bf16 weight ----------------
__global__ void build_w(const float* __restrict__ bw, const float* __restrict__ sw,
                        const float* __restrict__ ss, unsigned short* __restrict__ WcF) {
    const int o = blockIdx.x;    // output col 0..255
    const int i = threadIdx.x;   // input feature 0..255
    WcF[wcf_addr(o, i)] = (unsigned short)f2bf(bw[o * IN_F + i]);
    const float scal = ss[o * IN_F + i];
    const float4* swv = reinterpret_cast<const float4*>(sw + (size_t)(o * IN_F + i) * 8);
    float4 s0 = swv[0], s1 = swv[1];
    uint4 wv;
    wv.x = f2bf(s0.x * scal) | (f2bf(s0.y * scal) << 16);
    wv.y = f2bf(s0.z * scal) | (f2bf(s0.w * scal) << 16);
    wv.z = f2bf(s1.x * scal) | (f2bf(s1.y * scal) << 16);
    wv.w = f2bf(s1.z * scal) | (f2bf(s1.w * scal) << 16);
    *reinterpret_cast<uint4*>(WcF + wcf_addr(o, IN_F + i * 8)) = wv;
}

// ---------------- kernel 2: fused GEMM, 512 threads, K-split waves ----------------
// A LDS layout per buffer: addr(row, g) = row*128B + ((g ^ (row&7))*16B)
__launch_bounds__(512, 4)
__global__ void kan_fused(const float* __restrict__ x, const unsigned short* __restrict__ WcF,
                          float* __restrict__ out) {
    __shared__ __align__(16) unsigned short As[4][64 * 64];    // 32 KB

    const int bid = blockIdx.x;
    const int row0 = bid * 64;
    const int tid = threadIdx.x;
    const int lane = tid & 63;
    const int w = tid >> 6;            // wave id 0..7
    const int kh = w >> 2;             // 0..1 : K-half of each chunk
    const int wn = w & 3;              // 0..3 : 64-col quarter
    const int l15 = lane & 15;
    const int q = lane >> 4;

    // A-expansion mapping (each element once, coalesced x reads):
    //   thread -> (row = tid>>3, g8 = tid&7); owns 16B k-segment g8 of its row.
    const int erow = tid >> 3;         // 0..63
    const int g8   = tid & 7;          // 0..7

    f32x4 acc[4][4] = {};              // wave-tile 64 rows x 64 cols (half-K)
    bf16x8 bE[4], bO[4];               // B frag reg dbuf (own kh only)
    float x0, x1, x2, x3;              // basis x prefetch sets (chunk-4)&3

    const unsigned short* wbase = WcF + (size_t)lane * 8;

    auto load_b = [&](int kc, bf16x8* dst) {
#pragma unroll
        for (int nt = 0; nt < 4; ++nt)
            dst[nt] = *reinterpret_cast<const bf16x8*>(
                wbase + ((size_t)((kc * 2 + kh) * 16 + wn * 4 + nt)) * 512);
    };
    auto load_x_silu = [&](int c, float4& a, float4& b) {
        const float* xp = x + (size_t)(row0 + erow) * IN_F + c * 64 + g8 * 8;
        a = reinterpret_cast<const float4*>(xp)[0];
        b = reinterpret_cast<const float4*>(xp)[1];
    };
    auto load_x_bas = [&](int c, float& v) {
        v = x[(size_t)(row0 + erow) * IN_F + (c - 4) * 8 + g8];
    };
    auto expand_silu = [&](float4 a, float4 b, uint4& w0) {
        w0.x = cvtpk(silu_f(a.x), silu_f(a.y));
        w0.y = cvtpk(silu_f(a.z), silu_f(a.w));
        w0.z = cvtpk(silu_f(b.x), silu_f(b.y));
        w0.w = cvtpk(silu_f(b.z), silu_f(b.w));
    };
    auto write_a = [&](unsigned short* Ab, const uint4& w0) {
        *reinterpret_cast<uint4*>(Ab + erow * 64 + ((g8 ^ (erow & 7)) << 3)) = w0;
    };
    auto mfma_chunk = [&](const unsigned short* Ab, const bf16x8* bv) {
        const int g0 = kh * 4 + q;     // this wave's K-half
#pragma unroll
        for (int mt = 0; mt < 4; ++mt) {
            int r = mt * 16 + l15;
            bf16x8 a = *reinterpret_cast<const bf16x8*>(
                Ab + r * 64 + ((g0 ^ (r & 7)) << 3));
            __builtin_amdgcn_s_setprio(1);
#pragma unroll
            for (int nt = 0; nt < 4; ++nt)
                acc[mt][nt] = __builtin_amdgcn_mfma_f32_16x16x32_bf16(
                    a, bv[nt], acc[mt][nt], 0, 0, 0);
            __builtin_amdgcn_s_setprio(0);
        }
    };

    // ---- prologue: chunks 0,1 expanded+written; chunk 2,3 x staged; B(0) ----
    float4 s2a, s2b, s3a, s3b;
    {
        float4 a, b; uint4 t;
        load_x_silu(0, a, b);
        load_x_silu(1, s2a, s2b);      // reuse regs briefly for chunk 1
        load_x_silu(2, s3a, s3b);      // chunk 2 (held into SS0)
        load_b(0, bE);
        load_x_bas(4, x0);
        load_x_bas(5, x1);
        expand_silu(a, b, t);          write_a(&As[0][0], t);
        expand_silu(s2a, s2b, t);      write_a(&As[1][0], t);
        load_x_silu(3, s2a, s2b);      // chunk 3 (held into SS0)
        // s3a/s3b = chunk 2, s2a/s2b = chunk 3 from here on
    }
    block_sync_lds();

    // ---- superstep 0: silu chunks 2,3 into bufs 2,3; mfma chunks 0,1 ----
    load_b(1, bO);
    {
        uint4 a2, a3;
        expand_silu(s3a, s3b, a2);
        expand_silu(s2a, s2b, a3);
        write_a(&As[2][0], a2);
        write_a(&As[3][0], a3);
    }
    mfma_chunk(&As[0][0], bE);
    load_b(2, bE);
    mfma_chunk(&As[1][0], bO);
    block_sync_lds();

    // ---- supersteps 1..16 (basis region), pairs {odd, even} ----
    for (int t = 0; t < 8; ++t) {
        {   // odd: chunks 4t+2,4t+3 from bufs 2,3; write chunks 4t+4,4t+5 -> 0,1
            const int kc = 4 * t + 2;
            load_b(kc + 1, bO);
            load_x_bas(kc + 4, x2);    // chunks 4t+6,4t+7
            load_x_bas(kc + 5, x3);
            uint4 wa0, wa1;
            if (kh == 0) {
                wa0 = basis16(x0); wa1 = basis16(x1);
                write_a(&As[0][0], wa0); write_a(&As[1][0], wa1);
                mfma_chunk(&As[2][0], bE);
                load_b(kc + 2, bE);
                mfma_chunk(&As[3][0], bO);
            } else {
                mfma_chunk(&As[2][0], bE);
                load_b(kc + 2, bE);
                mfma_chunk(&As[3][0], bO);
                wa0 = basis16(x0); wa1 = basis16(x1);
                write_a(&As[0][0], wa0); write_a(&As[1][0], wa1);
            }
            block_sync_lds();
        }
        {   // even: chunks 4t+4,4t+5 from bufs 0,1; write chunks 4t+6,4t+7 -> 2,3
            const int kc2 = 4 * t + 4;
            load_b(kc2 + 1, bO);
            if (kc2 + 5 < NCHUNK) {    // skip at t=7 (chunks 36,37 don't exist)
                load_x_bas(kc2 + 4, x0);
                load_x_bas(kc2 + 5, x1);
            }
            uint4 wa0, wa1;
            if (kh == 0) {
                wa0 = basis16(x2); wa1 = basis16(x3);
                write_a(&As[2][0], wa0); write_a(&As[3][0], wa1);
                mfma_chunk(&As[0][0], bE);
                load_b(kc2 + 2, bE);
                mfma_chunk(&As[1][0], bO);
            } else {
                mfma_chunk(&As[0][0], bE);
                load_b(kc2 + 2, bE);
                mfma_chunk(&As[1][0], bO);
                wa0 = basis16(x2); wa1 = basis16(x3);
                write_a(&As[2][0], wa0); write_a(&As[3][0], wa1);
            }
            block_sync_lds();
        }
    }

    // ---- tail: chunks 34,35 (bufs 2,3), no expand ----
    load_b(35, bO);
    mfma_chunk(&As[2][0], bE);         // bE = B(34) from even t=7
    mfma_chunk(&As[3][0], bO);

    // ---- kh-pair reduction via LDS (As repurposed: 32 KB = 2 x 16 KB slots),
    //      then store. round r handles wn in {2r, 2r+1}; slot = wn&1.
    float* red = reinterpret_cast<float*>(&As[0][0]);
    const int slot = wn & 1;
#pragma unroll
    for (int round = 0; round < 2; ++round) {
        block_sync_lds();
        if ((wn >> 1) == round && kh == 1) {
#pragma unroll
            for (int mt = 0; mt < 4; ++mt)
#pragma unroll
                for (int nt = 0; nt < 4; ++nt)
#pragma unroll
                    for (int r = 0; r < 4; ++r)
                        red[slot * 4096 + (mt * 16 + q * 4 + r) * 64 + nt * 16 + l15] =
                            acc[mt][nt][r];
        }
        block_sync_lds();
        if ((wn >> 1) == round && kh == 0) {
#pragma unroll
            for (int mt = 0; mt < 4; ++mt)
#pragma unroll
                for (int nt = 0; nt < 4; ++nt)
#pragma unroll
                    for (int r = 0; r < 4; ++r) {
                        float v = acc[mt][nt][r] +
                                  red[slot * 4096 + (mt * 16 + q * 4 + r) * 64 + nt * 16 + l15];
                        out[(size_t)(row0 + mt * 16 + q * 4 + r) * OUT_F +
                            wn * 64 + nt * 16 + l15] = v;
                    }
        }
    }
}

extern "C" void kernel_launch(void* const* d_in, const int* in_sizes, int n_in,
                              void* d_out, int out_size, void* d_ws, size_t ws_size,
                              hipStream_t stream) {
    const float* x  = (const float*)d_in[0];
    const float* bw = (const float*)d_in[1];
    const float* sw = (const float*)d_in[2];
    const float* ss = (const float*)d_in[3];
    unsigned short* WcF = (unsigned short*)d_ws;                // 1.18 MB

    build_w<<<dim3(OUT_F), dim3(IN_F), 0, stream>>>(bw, sw, ss, WcF);

    const int B_ROWS = in_sizes[0] / IN_F;                      // 32768
    kan_fused<<<dim3(B_ROWS / 64), dim3(512), 0, stream>>>(
        x, WcF, (float*)d_out);
}

// Round 11
// 138.691 us; speedup vs baseline: 2.1329x; 2.1329x over previous
//
#include <hip/hip_runtime.h>
#include <stdint.h>

// KANLinear fused MFMA GEMM, R15: R14 (K-split waves, 2 blocks/CU) repaired.
//   R14 post-mortem: __launch_bounds__(512,4) capped VGPR at 64 < the ~120-reg
//   working set -> acc spilled to scratch -> 1 GB scratch traffic = 222us.
//   Fix: (512,2) -> 128-VGPR cap (R13 precedent, fits, no spill); hardware can
//   still co-schedule 2 blocks/CU (128 VGPR = 4 waves/SIMD, 2x32KB LDS fits).
//   Also: epilogue kh-reduction LDS XOR-swizzle (col ^= ((row>>2)&3)<<4) to
//   kill its 4-way bank conflict (524K counts in R14).
//   Structure unchanged vs R14: 8 waves = 2 kh x 4 wn, wave = all 64 rows x
//   64-col quarter over HALF of K; B loads dedup'd; superstep-2 schedule;
//   lgkm-only barriers; kh-stagger of expand vs MFMA.
//   64x256 tile, 512 thr, grid 512 (2 blk/CU), LDS 32 KB (A 4-buf only).
//   C = A @ W^T, A (B x 2304) = [silu(x) | bases(x)], W (256 x 2304) bf16 in ws.

#define IN_F 256
#define OUT_F 256
#define KDIM 2304 /* 256 silu + 256*8 basis */
#define BK 64
#define NCHUNK (KDIM / BK) /* 36 */

typedef float f32x4 __attribute__((ext_vector_type(4)));
typedef short bf16x8 __attribute__((ext_vector_type(8)));

__device__ __forceinline__ uint32_t f2bf(float f) {
    union { float f; uint32_t u; } c; c.f = f;
    uint32_t u = c.u;
    return (u + 0x7FFFu + ((u >> 16) & 1u)) >> 16;   // RNE
}

__device__ __forceinline__ uint32_t cvtpk(float lo, float hi) {
    uint32_t r;
    asm("v_cvt_pk_bf16_f32 %0, %1, %2" : "=v"(r) : "v"(lo), "v"(hi));
    return r;
}

__device__ __forceinline__ float silu_f(float v) {
    return v / (1.0f + __expf(-v));
}

// LDS-only block barrier: waits LDS ops but leaves the VMEM queue in flight.
__device__ __forceinline__ void block_sync_lds() {
    __builtin_amdgcn_sched_barrier(0);
    asm volatile("s_waitcnt lgkmcnt(0)" ::: "memory");
    __builtin_amdgcn_sched_barrier(0);
    __builtin_amdgcn_s_barrier();
    __builtin_amdgcn_sched_barrier(0);
}

// cubic B-spline: 16B fragment (8 bf16 coef slots) for one (row, feat) element.
__device__ __forceinline__ uint4 basis16(float xx) {
    float u = __builtin_fmaf(xx, 2.5f, 5.5f);   // (x - grid0)/h
    float jf = floorf(u);
    float t = u - jf;
    int j0 = (int)jf;
    float t2 = t * t, t3 = t2 * t;
    float p3 = t3 * (1.0f / 6.0f);
    float p2 = __builtin_fmaf(t3, -0.5f,
               __builtin_fmaf(t2, 0.5f, __builtin_fmaf(t, 0.5f, 1.0f / 6.0f)));
    float p1 = __builtin_fmaf(t3, 0.5f, __builtin_fmaf(t2, -1.0f, 2.0f / 3.0f));
    float omt = 1.0f - t;
    float p0 = omt * omt * omt * (1.0f / 6.0f);
    const int s0 = j0 - 3;
    int ds = s0 >> 1;                            // arithmetic: floor-div ok
    if ((unsigned)j0 > 10u) ds = 9;              // out of grid -> no dword match
    const bool odd = (s0 & 1) != 0;
    uint32_t v0 = cvtpk(odd ? 0.0f : p0, odd ? p0 : p1);
    uint32_t v1 = cvtpk(odd ? p1 : p2, odd ? p2 : p3);
    uint32_t v2 = odd ? cvtpk(p3, 0.0f) : 0u;
    uint4 r;
    r.x = (ds == 0) ? v0 : (ds == -1) ? v1 : (ds == -2) ? v2 : 0u;
    r.y = (ds == 1) ? v0 : (ds ==  0) ? v1 : (ds == -1) ? v2 : 0u;
    r.z = (ds == 2) ? v0 : (ds ==  1) ? v1 : (ds ==  0) ? v2 : 0u;
    r.w = (ds == 3) ? v0 : (ds ==  2) ? v1 : (ds ==  1) ? v2 : 0u;
    return r;
}

// fragment-native Wc address (bf16 units): W[col][kc*64+kkh*32+q*8+e]
__device__ __forceinline__ size_t wcf_addr(int col, int k) {
    const int kc = k >> 6, kkh = (k >> 5) & 1, q = (k >> 3) & 3, e = k & 7;
    return ((size_t)((kc * 2 + kkh) * 16 + (col >> 4))) * 512 +
           (size_t)(q * 16 + (col & 15)) * 8 + e;
}

// ---------------- kernel 1: fragment-native bf16 weight ----------------
__global__ void build_w(const float* __restrict__ bw, const float* __restrict__ sw,
                        const float* __restrict__ ss, unsigned short* __restrict__ WcF) {
    const int o = blockIdx.x;    // output col 0..255
    const int i = threadIdx.x;   // input feature 0..255
    WcF[wcf_addr(o, i)] = (unsigned short)f2bf(bw[o * IN_F + i]);
    const float scal = ss[o * IN_F + i];
    const float4* swv = reinterpret_cast<const float4*>(sw + (size_t)(o * IN_F + i) * 8);
    float4 s0 = swv[0], s1 = swv[1];
    uint4 wv;
    wv.x = f2bf(s0.x * scal) | (f2bf(s0.y * scal) << 16);
    wv.y = f2bf(s0.z * scal) | (f2bf(s0.w * scal) << 16);
    wv.z = f2bf(s1.x * scal) | (f2bf(s1.y * scal) << 16);
    wv.w = f2bf(s1.z * scal) | (f2bf(s1.w * scal) << 16);
    *reinterpret_cast<uint4*>(WcF + wcf_addr(o, IN_F + i * 8)) = wv;
}

// ---------------- kernel 2: fused GEMM, 512 threads, K-split waves ----------------
// A LDS layout per buffer: addr(row, g) = row*128B + ((g ^ (row&7))*16B)
__launch_bounds__(512, 2)
__global__ void kan_fused(const float* __restrict__ x, const unsigned short* __restrict__ WcF,
                          float* __restrict__ out) {
    __shared__ __align__(16) unsigned short As[4][64 * 64];    // 32 KB

    const int bid = blockIdx.x;
    const int row0 = bid * 64;
    const int tid = threadIdx.x;
    const int lane = tid & 63;
    const int w = tid >> 6;            // wave id 0..7
    const int kh = w >> 2;             // 0..1 : K-half of each chunk
    const int wn = w & 3;              // 0..3 : 64-col quarter
    const int l15 = lane & 15;
    const int q = lane >> 4;

    // A-expansion mapping (each element once, coalesced x reads):
    //   thread -> (row = tid>>3, g8 = tid&7); owns 16B k-segment g8 of its row.
    const int erow = tid >> 3;         // 0..63
    const int g8   = tid & 7;          // 0..7

    f32x4 acc[4][4] = {};              // wave-tile 64 rows x 64 cols (half-K)
    bf16x8 bE[4], bO[4];               // B frag reg dbuf (own kh only)
    float x0, x1, x2, x3;              // basis x prefetch sets (chunk-4)&3

    const unsigned short* wbase = WcF + (size_t)lane * 8;

    auto load_b = [&](int kc, bf16x8* dst) {
#pragma unroll
        for (int nt = 0; nt < 4; ++nt)
            dst[nt] = *reinterpret_cast<const bf16x8*>(
                wbase + ((size_t)((kc * 2 + kh) * 16 + wn * 4 + nt)) * 512);
    };
    auto load_x_silu = [&](int c, float4& a, float4& b) {
        const float* xp = x + (size_t)(row0 + erow) * IN_F + c * 64 + g8 * 8;
        a = reinterpret_cast<const float4*>(xp)[0];
        b = reinterpret_cast<const float4*>(xp)[1];
    };
    auto load_x_bas = [&](int c, float& v) {
        v = x[(size_t)(row0 + erow) * IN_F + (c - 4) * 8 + g8];
    };
    auto expand_silu = [&](float4 a, float4 b, uint4& w0) {
        w0.x = cvtpk(silu_f(a.x), silu_f(a.y));
        w0.y = cvtpk(silu_f(a.z), silu_f(a.w));
        w0.z = cvtpk(silu_f(b.x), silu_f(b.y));
        w0.w = cvtpk(silu_f(b.z), silu_f(b.w));
    };
    auto write_a = [&](unsigned short* Ab, const uint4& w0) {
        *reinterpret_cast<uint4*>(Ab + erow * 64 + ((g8 ^ (erow & 7)) << 3)) = w0;
    };
    auto mfma_chunk = [&](const unsigned short* Ab, const bf16x8* bv) {
        const int g0 = kh * 4 + q;     // this wave's K-half
#pragma unroll
        for (int mt = 0; mt < 4; ++mt) {
            int r = mt * 16 + l15;
            bf16x8 a = *reinterpret_cast<const bf16x8*>(
                Ab + r * 64 + ((g0 ^ (r & 7)) << 3));
            __builtin_amdgcn_s_setprio(1);
#pragma unroll
            for (int nt = 0; nt < 4; ++nt)
                acc[mt][nt] = __builtin_amdgcn_mfma_f32_16x16x32_bf16(
                    a, bv[nt], acc[mt][nt], 0, 0, 0);
            __builtin_amdgcn_s_setprio(0);
        }
    };

    // ---- prologue: chunks 0,1 expanded+written; chunk 2,3 x staged; B(0) ----
    float4 s2a, s2b, s3a, s3b;
    {
        float4 a, b; uint4 t;
        load_x_silu(0, a, b);
        load_x_silu(1, s2a, s2b);      // reuse regs briefly for chunk 1
        load_x_silu(2, s3a, s3b);      // chunk 2 (held into SS0)
        load_b(0, bE);
        load_x_bas(4, x0);
        load_x_bas(5, x1);
        expand_silu(a, b, t);          write_a(&As[0][0], t);
        expand_silu(s2a, s2b, t);      write_a(&As[1][0], t);
        load_x_silu(3, s2a, s2b);      // chunk 3 (held into SS0)
        // s3a/s3b = chunk 2, s2a/s2b = chunk 3 from here on
    }
    block_sync_lds();

    // ---- superstep 0: silu chunks 2,3 into bufs 2,3; mfma chunks 0,1 ----
    load_b(1, bO);
    {
        uint4 a2, a3;
        expand_silu(s3a, s3b, a2);
        expand_silu(s2a, s2b, a3);
        write_a(&As[2][0], a2);
        write_a(&As[3][0], a3);
    }
    mfma_chunk(&As[0][0], bE);
    load_b(2, bE);
    mfma_chunk(&As[1][0], bO);
    block_sync_lds();

    // ---- supersteps 1..16 (basis region), pairs {odd, even} ----
    for (int t = 0; t < 8; ++t) {
        {   // odd: chunks 4t+2,4t+3 from bufs 2,3; write chunks 4t+4,4t+5 -> 0,1
            const int kc = 4 * t + 2;
            load_b(kc + 1, bO);
            load_x_bas(kc + 4, x2);    // chunks 4t+6,4t+7
            load_x_bas(kc + 5, x3);
            uint4 wa0, wa1;
            if (kh == 0) {
                wa0 = basis16(x0); wa1 = basis16(x1);
                write_a(&As[0][0], wa0); write_a(&As[1][0], wa1);
                mfma_chunk(&As[2][0], bE);
                load_b(kc + 2, bE);
                mfma_chunk(&As[3][0], bO);
            } else {
                mfma_chunk(&As[2][0], bE);
                load_b(kc + 2, bE);
                mfma_chunk(&As[3][0], bO);
                wa0 = basis16(x0); wa1 = basis16(x1);
                write_a(&As[0][0], wa0); write_a(&As[1][0], wa1);
            }
            block_sync_lds();
        }
        {   // even: chunks 4t+4,4t+5 from bufs 0,1; write chunks 4t+6,4t+7 -> 2,3
            const int kc2 = 4 * t + 4;
            load_b(kc2 + 1, bO);
            if (kc2 + 5 < NCHUNK) {    // skip at t=7 (chunks 36,37 don't exist)
                load_x_bas(kc2 + 4, x0);
                load_x_bas(kc2 + 5, x1);
            }
            uint4 wa0, wa1;
            if (kh == 0) {
                wa0 = basis16(x2); wa1 = basis16(x3);
                write_a(&As[2][0], wa0); write_a(&As[3][0], wa1);
                mfma_chunk(&As[0][0], bE);
                load_b(kc2 + 2, bE);
                mfma_chunk(&As[1][0], bO);
            } else {
                mfma_chunk(&As[0][0], bE);
                load_b(kc2 + 2, bE);
                mfma_chunk(&As[1][0], bO);
                wa0 = basis16(x2); wa1 = basis16(x3);
                write_a(&As[2][0], wa0); write_a(&As[3][0], wa1);
            }
            block_sync_lds();
        }
    }

    // ---- tail: chunks 34,35 (bufs 2,3), no expand ----
    load_b(35, bO);
    mfma_chunk(&As[2][0], bE);         // bE = B(34) from even t=7
    mfma_chunk(&As[3][0], bO);

    // ---- kh-pair reduction via LDS (As repurposed: 2 x 16 KB slots).
    //      XOR-swizzled (col ^= ((row>>2)&3)<<4) -> free 2-way conflicts only.
    float* red = reinterpret_cast<float*>(&As[0][0]);
    const int slot = wn & 1;
    auto ridx = [&](int row, int col) {
        return row * 64 + (col ^ ((((row) >> 2) & 3) << 4));
    };
#pragma unroll
    for (int round = 0; round < 2; ++round) {
        block_sync_lds();
        if ((wn >> 1) == round && kh == 1) {
#pragma unroll
            for (int mt = 0; mt < 4; ++mt)
#pragma unroll
                for (int nt = 0; nt < 4; ++nt)
#pragma unroll
                    for (int r = 0; r < 4; ++r)
                        red[slot * 4096 + ridx(mt * 16 + q * 4 + r, nt * 16 + l15)] =
                            acc[mt][nt][r];
        }
        block_sync_lds();
        if ((wn >> 1) == round && kh == 0) {
#pragma unroll
            for (int mt = 0; mt < 4; ++mt)
#pragma unroll
                for (int nt = 0; nt < 4; ++nt)
#pragma unroll
                    for (int r = 0; r < 4; ++r) {
                        float v = acc[mt][nt][r] +
                                  red[slot * 4096 + ridx(mt * 16 + q * 4 + r, nt * 16 + l15)];
                        out[(size_t)(row0 + mt * 16 + q * 4 + r) * OUT_F +
                            wn * 64 + nt * 16 + l15] = v;
                    }
        }
    }
}

extern "C" void kernel_launch(void* const* d_in, const int* in_sizes, int n_in,
                              void* d_out, int out_size, void* d_ws, size_t ws_size,
                              hipStream_t stream) {
    const float* x  = (const float*)d_in[0];
    const float* bw = (const float*)d_in[1];
    const float* sw = (const float*)d_in[2];
    const float* ss = (const float*)d_in[3];
    unsigned short* WcF = (unsigned short*)d_ws;                // 1.18 MB

    build_w<<<dim3(OUT_F), dim3(IN_F), 0, stream>>>(bw, sw, ss, WcF);

    const int B_ROWS = in_sizes[0] / IN_F;                      // 32768
    kan_fused<<<dim3(B_ROWS / 64), dim3(512), 0, stream>>>(
        x, WcF, (float*)d_out);
}